// Round 1
// baseline (1285.867 us; speedup 1.0000x reference)
//
#include <hip/hip_runtime.h>
#include <math.h>

#define WAVES 8
#define BLOCK (WAVES*64)
#define NPTS 4096
#define NBATCH 4

static constexpr float KSCALE     = 1.4426950408889634f / 1e-4f;   // log2(e)/eps
static constexpr float EPSLN2     = 1e-4f * 0.6931471805599453f;   // eps*ln(2)
static constexpr float NEGEPSLOGW = 8.31776616671934e-4f;          // -eps * (-log(4096))

__device__ __forceinline__ float fexp2(float x){
#if __has_builtin(__builtin_amdgcn_exp2f)
  return __builtin_amdgcn_exp2f(x);
#else
  return exp2f(x);
#endif
}
__device__ __forceinline__ float flog2(float x){
#if __has_builtin(__builtin_amdgcn_logf)
  return __builtin_amdgcn_logf(x);
#else
  return log2f(x);
#endif
}

// Generic softmin update. One launch handles TWO independent problems
// (256 blocks each). Per block: 64 output rows, all 4096 columns.
// lane = row, wave = 512-column segment; columns staged in LDS as
// (qx,qy,qz, Atilde) where Atilde=(h[m]-0.5|q|^2)*log2e/eps.
// out[n] = 0.5|p_n|^2 - eps*logw - eps*ln2*(M + log2(S))  [mode 0]
//        = 0.5*(h[n] + above)                             [mode 1, symmetric avg]
__global__ __launch_bounds__(BLOCK, 4) void softmin_kernel(
    const float* __restrict__ rowA, int rsA, const float* __restrict__ colA, int csA,
    const float* __restrict__ hA, float* __restrict__ outA, int modeA,
    const float* __restrict__ rowB, int rsB, const float* __restrict__ colB, int csB,
    const float* __restrict__ hB, float* __restrict__ outB, int modeB)
{
  extern __shared__ float smem[];            // 4096 * float4 = 64KB
  float4* qs = (float4*)smem;

  int bid = blockIdx.x;
  const float *rowp, *colp, *h; float* outp; int rs, cs, mode;
  if (bid < 256) { rowp=rowA; colp=colA; h=hA; outp=outA; rs=rsA; cs=csA; mode=modeA; }
  else           { rowp=rowB; colp=colB; h=hB; outp=outB; rs=rsB; cs=csB; mode=modeB; }
  int lb = bid & 255;
  int b = lb >> 6;
  int rowblk = lb & 63;

  int tid = threadIdx.x;
  int wave = tid >> 6, lane = tid & 63;

  // stage all 4096 columns of this batch into LDS
  for (int k = 0; k < NPTS/BLOCK; ++k) {
    int m = tid + k*BLOCK;
    const float* q = colp + (size_t)(b*NPTS + m) * cs;
    float qx = q[0], qy = q[1], qz = q[2];
    float q2h = 0.5f*(qx*qx + qy*qy + qz*qz);
    float At = (h[b*NPTS + m] - q2h) * KSCALE;
    qs[m] = make_float4(qx, qy, qz, At);
  }

  // this lane's row point
  int row = rowblk*64 + lane;
  int ridx = b*NPTS + row;
  const float* p = rowp + (size_t)ridx * rs;
  float px = p[0], py = p[1], pz = p[2];
  float chalf = 0.5f*(px*px + py*py + pz*pz);
  float ptx = px*KSCALE, pty = py*KSCALE, ptz = pz*KSCALE;

  __syncthreads();

  // online LSE over this wave's 512-column segment, K=4 chunks
  int m0 = wave * (NPTS/WAVES);
  float M = -INFINITY, S = 0.f;
  for (int c4 = 0; c4 < (NPTS/WAVES)/4; ++c4) {
    int mb = m0 + c4*4;
    float4 a0 = qs[mb+0], a1 = qs[mb+1], a2 = qs[mb+2], a3 = qs[mb+3];
    float t0 = fmaf(ptx, a0.x, fmaf(pty, a0.y, fmaf(ptz, a0.z, a0.w)));
    float t1 = fmaf(ptx, a1.x, fmaf(pty, a1.y, fmaf(ptz, a1.z, a1.w)));
    float t2 = fmaf(ptx, a2.x, fmaf(pty, a2.y, fmaf(ptz, a2.z, a2.w)));
    float t3 = fmaf(ptx, a3.x, fmaf(pty, a3.y, fmaf(ptz, a3.z, a3.w)));
    float Mc = fmaxf(fmaxf(t0,t1), fmaxf(t2,t3));
    float Mn = fmaxf(M, Mc);
    float sc = fexp2(M - Mn);
    float e  = fexp2(t0-Mn) + fexp2(t1-Mn) + fexp2(t2-Mn) + fexp2(t3-Mn);
    S = fmaf(S, sc, e);
    M = Mn;
  }

  __syncthreads();                     // qs dead; alias first 4KB for combine
  float2* comb = (float2*)smem;
  comb[wave*64 + lane] = make_float2(M, S);
  __syncthreads();

  if (wave == 0) {
    float2 v[WAVES];
    float Mstar = -INFINITY;
    #pragma unroll
    for (int w = 0; w < WAVES; ++w) { v[w] = comb[w*64 + lane]; Mstar = fmaxf(Mstar, v[w].x); }
    float Ssum = 0.f;
    #pragma unroll
    for (int w = 0; w < WAVES; ++w) Ssum = fmaf(v[w].y, fexp2(v[w].x - Mstar), Ssum);
    float lse2 = Mstar + flog2(Ssum);
    float res = fmaf(-EPSLN2, lse2, chalf + NEGEPSLOGW);
    if (mode) res = 0.5f*(h[ridx] + res);
    outp[ridx] = res;
  }
}

__global__ void reduce_kernel(const float* __restrict__ fab, const float* __restrict__ faa,
                              const float* __restrict__ gab, const float* __restrict__ gbb,
                              float* __restrict__ out)
{
  int b = blockIdx.x;
  int tid = threadIdx.x;
  float s = 0.f;
  for (int i = tid; i < NPTS; i += 256) {
    int idx = b*NPTS + i;
    s += (fab[idx] - faa[idx]) + (gab[idx] - gbb[idx]);
  }
  for (int off = 32; off > 0; off >>= 1) s += __shfl_down(s, off, 64);
  __shared__ float red[4];
  if ((tid & 63) == 0) red[tid >> 6] = s;
  __syncthreads();
  if (tid == 0) out[b] = (red[0]+red[1]+red[2]+red[3]) * (1.0f/NPTS);
}

extern "C" void kernel_launch(void* const* d_in, const int* in_sizes, int n_in,
                              void* d_out, int out_size, void* d_ws, size_t ws_size,
                              hipStream_t stream)
{
  const float* x = (const float*)d_in[0];   // (4,4096,3)
  const float* y = (const float*)d_in[1];   // (4,4096,4), first 3 comps used
  float* ws = (float*)d_ws;
  const int P = NBATCH * NPTS;              // 16384
  float* g_ab  = ws + 0*P;
  float* f_aa0 = ws + 1*P;
  float* g_bb0 = ws + 2*P;
  float* f_ab  = ws + 3*P;
  float* f_aa1 = ws + 4*P;
  float* g_bb1 = ws + 5*P;

  // zero-init g_ab, f_aa0, g_bb0 (contiguous)
  hipMemsetAsync(ws, 0, 3*(size_t)P*sizeof(float), stream);

  size_t lds = (size_t)NPTS * 4 * sizeof(float);   // 64KB
  dim3 grid(512), block(BLOCK);

  for (int i = 0; i < 21; ++i) {
    float* fain  = (i & 1) ? f_aa1 : f_aa0;
    float* faout = (i & 1) ? f_aa0 : f_aa1;
    float* gbin  = (i & 1) ? g_bb1 : g_bb0;
    float* gbout = (i & 1) ? g_bb0 : g_bb1;
    int modeS = (i < 20) ? 1 : 0;    // averaged update except final softmin
    // phase 1: f_ab update (needs g_ab)  ||  f_aa symmetric step
    softmin_kernel<<<grid, block, lds, stream>>>(
        x, 3, y, 4, g_ab, f_ab, 0,
        x, 3, x, 3, fain, faout, modeS);
    // phase 2: g_ab update (needs f_ab)  ||  g_bb symmetric step
    softmin_kernel<<<grid, block, lds, stream>>>(
        y, 4, x, 3, f_ab, g_ab, 0,
        y, 4, y, 4, gbin, gbout, modeS);
  }
  // after i=20 (even): final buffers are f_aa1, g_bb1
  reduce_kernel<<<dim3(4), dim3(256), 0, stream>>>(f_ab, f_aa1, g_ab, g_bb1, (float*)d_out);
}